// Round 1
// baseline (698.392 us; speedup 1.0000x reference)
//
#include <hip/hip_runtime.h>

#define Vn 128
#define En 32
#define Hn 128
#define Bn 4
#define Sn 512
#define G4H 512   // 4*Hn

__device__ __forceinline__ float fsigmoid(float x) {
    // 1/(1+e^-x): e^-x may overflow to inf for very negative x -> 1/inf = 0, safe.
    return 1.0f / (1.0f + __expf(-x));
}

__device__ __forceinline__ float ftanh(float x) {
    // sign(x)*(1 - 2/(1+e^{2|x|})): e>=1 so never NaN, saturates to +-1.
    float ax = fabsf(x);
    float e  = __expf(2.0f * ax);
    float t  = 1.0f - 2.0f / (e + 1.0f);
    return copysignf(t, x);
}

// Sum across the 4 lanes of a DPP quad (lanes 4k..4k+3); result in all 4 lanes.
// quad_perm[1,0,3,2] = 0xB1 (xor 1), quad_perm[2,3,0,1] = 0x4E (xor 2).
__device__ __forceinline__ float quad_sum(float v) {
    int t1 = __builtin_amdgcn_update_dpp(0, __float_as_int(v), 0xB1, 0xF, 0xF, false);
    float a = v + __int_as_float(t1);
    int t2 = __builtin_amdgcn_update_dpp(0, __float_as_int(a), 0x4E, 0xF, 0xF, false);
    return a + __int_as_float(t2);
}

// ---------------------------------------------------------------------------
// Kernel A': Gtab[v][g] = (b_ih+b_hh)[g] + sum_e emb[v][e] * W_ih[g][e]
// Only V=128 distinct embedding rows exist -> precompute per-vocab gate
// pre-activations once.
// ---------------------------------------------------------------------------
__global__ __launch_bounds__(512) void k_gtab(
        const float* __restrict__ emb, const float* __restrict__ Wih,
        const float* __restrict__ bih, const float* __restrict__ bhh,
        float* __restrict__ Gtab) {
    int v = blockIdx.x;
    int g = threadIdx.x;
    __shared__ float e[En];
    if (g < En) e[g] = emb[v * En + g];
    __syncthreads();
    const float4* wr = (const float4*)(Wih + g * En);
    float acc = bih[g] + bhh[g];
#pragma unroll
    for (int i = 0; i < En / 4; i++) {
        float4 w4 = wr[i];
        acc += w4.x * e[4*i] + w4.y * e[4*i+1] + w4.z * e[4*i+2] + w4.w * e[4*i+3];
    }
    Gtab[v * G4H + g] = acc;
}

// ---------------------------------------------------------------------------
// Kernel B (R5 rewrite): LSTM recurrence. One block per batch, 512 threads.
// Thread (j = tid>>2, q = tid&3): owns gate rows {g*128+j, g=0..3} restricted
// to the stride-4-interleaved float4 chunks {q, q+4, ..., q+28} of K.
//
// vs R4:
//  * The 4 K-partials of each (gate,row) live in one DPP quad -> reduced with
//    2 quad_perm DPP-adds per gate. No part[] LDS round-trip, no serial
//    tid<128 phase (activation computed redundantly by all 4 quad lanes,
//    zero divergence), ONE barrier per step (hbuf double-buffered).
//  * Weights are loaded ONCE through a volatile pointer: volatile loads are
//    not rematerializable, so no per-iteration asm pins are needed. R4's
//    in-loop "+v" pins forced per-step register-class round-trips
//    (VGPR_Count=88 < 128 pinned floats => weights sat in AGPRs and were
//    copied to VGPRs every step -- the hidden ~2x VALU cost).
//  * Chunk interleave (chunk = q + 4*i) puts the 4 distinct broadcast
//    addresses of each hbuf ds_read_b128 on distinct banks (4q+16(i&1)).
// ---------------------------------------------------------------------------
__global__ __attribute__((amdgpu_flat_work_group_size(512, 512),
                          amdgpu_waves_per_eu(2, 2)))
void k_lstm(
        const float* __restrict__ Whh, const float* __restrict__ Gtab,
        const int* __restrict__ x,
        float* __restrict__ out, float* __restrict__ hT, float* __restrict__ cT) {
    int b   = blockIdx.x;
    int tid = threadIdx.x;
    int j   = tid >> 2;   // 0..127: row within each gate
    int q   = tid & 3;    // 0..3  : K-chunk class (DPP quad lane)

    __shared__ float hbuf[2][Hn];
    __shared__ int   xb[Sn];

    xb[tid] = x[b * Sn + tid];
    if (tid < 2 * Hn) ((float*)hbuf)[tid] = 0.0f;

    // Which gate's Gtab entry this quad lane contributes (exactly once/quad).
    float m0 = (q == 0) ? 1.0f : 0.0f;
    float m1 = (q == 1) ? 1.0f : 0.0f;
    float m2 = (q == 2) ? 1.0f : 0.0f;
    float m3 = (q == 3) ? 1.0f : 0.0f;

    // Loop-invariant weight preload: w[g][i] = W_hh[g*128+j][4*(q+4i) .. +3]
    // (128 floats). Volatile => cannot be rematerialized into the loop.
    float4 w[4][8];
#pragma unroll
    for (int g = 0; g < 4; g++) {
        const volatile float* row = Whh + (g * Hn + j) * Hn;
#pragma unroll
        for (int i = 0; i < 8; i++) {
            int c0 = 4 * (q + 4 * i);
            w[g][i].x = row[c0 + 0];
            w[g][i].y = row[c0 + 1];
            w[g][i].z = row[c0 + 2];
            w[g][i].w = row[c0 + 3];
        }
    }

    float c = 0.0f;
    float hlast = 0.0f;
    float* out_base = out + b * Sn * Hn + j;
    __syncthreads();

    for (int s = 0; s < Sn; s++) {
        int xs = xb[s];
        // gate q's pre-activation for row j (bias + x-path), L2-resident
        float gxv = Gtab[xs * G4H + q * Hn + j];

        // this thread's interleaved h chunks from the current buffer
        const float4* h4 = (const float4*)hbuf[s & 1];
        float4 hv[8];
#pragma unroll
        for (int i = 0; i < 8; i++) hv[i] = h4[q + 4 * i];

        float p0 = 0.f, p1 = 0.f, p2 = 0.f, p3 = 0.f;
#pragma unroll
        for (int i = 0; i < 8; i++) {
            p0 += w[0][i].x * hv[i].x + w[0][i].y * hv[i].y
                + w[0][i].z * hv[i].z + w[0][i].w * hv[i].w;
            p1 += w[1][i].x * hv[i].x + w[1][i].y * hv[i].y
                + w[1][i].z * hv[i].z + w[1][i].w * hv[i].w;
            p2 += w[2][i].x * hv[i].x + w[2][i].y * hv[i].y
                + w[2][i].z * hv[i].z + w[2][i].w * hv[i].w;
            p3 += w[3][i].x * hv[i].x + w[3][i].y * hv[i].y
                + w[3][i].z * hv[i].z + w[3][i].w * hv[i].w;
        }
        // fold the x-path term into the partial of the gate this lane owns
        p0 = fmaf(m0, gxv, p0);
        p1 = fmaf(m1, gxv, p1);
        p2 = fmaf(m2, gxv, p2);
        p3 = fmaf(m3, gxv, p3);

        // quad butterfly: full gate sums in ALL 4 lanes (no LDS, no barrier)
        float Si = quad_sum(p0);
        float Sf = quad_sum(p1);
        float Sg = quad_sum(p2);
        float So = quad_sum(p3);

        // redundant (x4) activation -- keeps c per-thread, zero divergence
        c = fsigmoid(Sf) * c + fsigmoid(Si) * ftanh(Sg);
        float h = fsigmoid(So) * ftanh(c);
        hlast = h;
        if (q == 0) {
            hbuf[(s & 1) ^ 1][j] = h;   // next step's buffer
            out_base[s * Hn] = h;
        }
        __syncthreads();   // single barrier: h(s) published before step s+1
    }
    if (q == 0) {
        hT[b * Hn + j] = hlast;
        cT[b * Hn + j] = c;
    }
}

// ---------------------------------------------------------------------------
// Kernel C: q = out@Wq.T + bq ; k = out@Wk.T + bk
// grid = B*S blocks, 256 threads (128 for q, 128 for k)
// ---------------------------------------------------------------------------
__global__ __launch_bounds__(256) void k_qk(
        const float* __restrict__ out, const float* __restrict__ Wq,
        const float* __restrict__ bq, const float* __restrict__ Wk,
        const float* __restrict__ bk, float* __restrict__ qo, float* __restrict__ ko) {
    int bs  = blockIdx.x;
    int tid = threadIdx.x;
    __shared__ float o[Hn];
    if (tid < Hn) o[tid] = out[bs * Hn + tid];
    __syncthreads();
    int h = tid & 127;
    const float* Wm = (tid < Hn) ? Wq : Wk;
    const float* bm = (tid < Hn) ? bq : bk;
    const float4* wr = (const float4*)(Wm + h * Hn);
    float acc = bm[h];
#pragma unroll
    for (int i = 0; i < Hn / 4; i++) {
        float4 w4 = wr[i];
        acc += w4.x * o[4*i] + w4.y * o[4*i+1] + w4.z * o[4*i+2] + w4.w * o[4*i+3];
    }
    float* dst = (tid < Hn) ? qo : ko;
    dst[bs * Hn + h] = acc;
}

// ---------------------------------------------------------------------------
// Kernel D: Bahdanau scores + causal softmax + ctx. Block per (b,t),
// 512 threads: exactly one score row index i per thread (t <= 511), so the
// score/tanh phase is loop-free. ctx phase: 16-way i-split x 32 float4
// columns, combined through LDS part[16][128].
// ---------------------------------------------------------------------------
__global__ __launch_bounds__(512) void k_attn(
        const float* __restrict__ qo, const float* __restrict__ ko,
        const float* __restrict__ vvec, const float* __restrict__ out,
        float* __restrict__ ctx) {
    int b   = blockIdx.x >> 9;
    int t   = blockIdx.x & (Sn - 1);
    int tid = threadIdx.x;
    __shared__ float qs[Hn];
    __shared__ float vs[Hn];
    __shared__ float sc[Sn];
    __shared__ float red[512];
    __shared__ float part[16][Hn];

    if (tid < Hn) {
        qs[tid] = qo[(b * Sn + t) * Hn + tid];
        vs[tid] = vvec[tid];
    }
    __syncthreads();

    // --- scores: thread tid handles key index i = tid (if <= t) ---
    float a = -1e30f;
    if (tid <= t) {
        const float4* kr = (const float4*)(ko + (b * Sn + tid) * Hn);
        float s = 0.0f;
#pragma unroll
        for (int u = 0; u < Hn / 4; u++) {
            float4 k4 = kr[u];
            s += vs[4*u]   * ftanh(qs[4*u]   + k4.x);
            s += vs[4*u+1] * ftanh(qs[4*u+1] + k4.y);
            s += vs[4*u+2] * ftanh(qs[4*u+2] + k4.z);
            s += vs[4*u+3] * ftanh(qs[4*u+3] + k4.w);
        }
        sc[tid] = s;
        a = s;
    }
    red[tid] = a;
    __syncthreads();
    for (int off = 256; off > 0; off >>= 1) {
        if (tid < off) red[tid] = fmaxf(red[tid], red[tid + off]);
        __syncthreads();
    }
    float m = red[0];
    __syncthreads();

    float ev = 0.0f;
    if (tid <= t) {
        ev = __expf(sc[tid] - m);
        sc[tid] = ev;
    }
    red[tid] = ev;
    __syncthreads();
    for (int off = 256; off > 0; off >>= 1) {
        if (tid < off) red[tid] += red[tid + off];
        __syncthreads();
    }
    float inv = 1.0f / red[0];
    __syncthreads();

    // --- ctx: i-slice = tid>>5 (16 slices), float4 column = tid&31 ---
    int hq = tid & 31;
    int is = tid >> 5;
    float4 acc = {0.0f, 0.0f, 0.0f, 0.0f};
    const float4* ob = (const float4*)(out + b * Sn * Hn);
    for (int i = is; i <= t; i += 16) {
        float s = sc[i];
        float4 o4 = ob[i * (Hn / 4) + hq];
        acc.x += s * o4.x; acc.y += s * o4.y;
        acc.z += s * o4.z; acc.w += s * o4.w;
    }
    ((float4*)part[is])[hq] = acc;
    __syncthreads();
    if (tid < Hn) {
        float ssum = 0.0f;
#pragma unroll
        for (int r = 0; r < 16; r++) ssum += part[r][tid];
        ctx[(b * Sn + t) * Hn + tid] = ssum * inv;
    }
}

// ---------------------------------------------------------------------------
// Kernel E: logits = [out, ctx] @ Wf.T + bf. Block per (b,s), 128 threads.
// ---------------------------------------------------------------------------
__global__ __launch_bounds__(128) void k_final(
        const float* __restrict__ out, const float* __restrict__ ctx,
        const float* __restrict__ Wf, const float* __restrict__ bf,
        float* __restrict__ logits) {
    int bs  = blockIdx.x;
    int tid = threadIdx.x;  // = vocab index
    __shared__ float oc[2 * Hn];
    oc[tid]      = out[bs * Hn + tid];
    oc[tid + Hn] = ctx[bs * Hn + tid];
    __syncthreads();
    const float4* wr = (const float4*)(Wf + tid * 2 * Hn);
    float acc = bf[tid];
#pragma unroll
    for (int i = 0; i < (2 * Hn) / 4; i++) {
        float4 w4 = wr[i];
        acc += w4.x * oc[4*i] + w4.y * oc[4*i+1] + w4.z * oc[4*i+2] + w4.w * oc[4*i+3];
    }
    logits[bs * Vn + tid] = acc;
}

extern "C" void kernel_launch(void* const* d_in, const int* in_sizes, int n_in,
                              void* d_out, int out_size, void* d_ws, size_t ws_size,
                              hipStream_t stream) {
    const int*   x   = (const int*)d_in[0];
    const float* emb = (const float*)d_in[1];
    const float* Wih = (const float*)d_in[2];
    const float* Whh = (const float*)d_in[3];
    const float* bih = (const float*)d_in[4];
    const float* bhh = (const float*)d_in[5];
    const float* Wq  = (const float*)d_in[6];
    const float* bq  = (const float*)d_in[7];
    const float* Wk  = (const float*)d_in[8];
    const float* bk  = (const float*)d_in[9];
    const float* v   = (const float*)d_in[10];
    const float* Wf  = (const float*)d_in[11];
    const float* bf  = (const float*)d_in[12];

    float* logits = (float*)d_out;                 // (B,S,V) = 262144
    float* hT     = logits + Bn * Sn * Vn;         // (B,H)   = 512
    float* cT     = hT + Bn * Hn;                  // (B,H)   = 512

    float* ws   = (float*)d_ws;
    float* Gtab = ws;                               // V*4H   = 65536 floats
    float* outb = ws + 65536;                       // B*S*H  = 262144
    float* qo   = ws + 65536 + 262144;
    float* ko   = ws + 65536 + 2 * 262144;
    float* ctx  = ws + 65536 + 3 * 262144;

    k_gtab<<<Vn, 512, 0, stream>>>(emb, Wih, bih, bhh, Gtab);
    k_lstm<<<Bn, 512, 0, stream>>>(Whh, Gtab, x, outb, hT, cT);
    k_qk<<<Bn * Sn, 256, 0, stream>>>(outb, Wq, bq, Wk, bk, qo, ko);
    k_attn<<<Bn * Sn, 512, 0, stream>>>(qo, ko, v, outb, ctx);
    k_final<<<Bn * Sn, 128, 0, stream>>>(outb, ctx, Wf, bf, logits);
}